// Round 11
// baseline (173.061 us; speedup 1.0000x reference)
//
#include <hip/hip_runtime.h>

#define G_    1024
#define TPB   512
#define INF_F 3.4e38f

typedef __attribute__((ext_vector_type(8))) short short8;
typedef __attribute__((ext_vector_type(4))) float f32x4;

__device__ __forceinline__ float elu_fast(float x) { return x > 0.f ? x : __expf(x) - 1.f; }
__device__ __forceinline__ float elu_ref(float x)  { return x > 0.f ? x : expm1f(x); }

// bf16 tile rows: rotation by 8 shorts (16B) keeps short8 frag loads aligned; 2-way banks
#define RB(r, c)     ((r)*128 + (((c) + 8*(r)) & 127))
// bsrc rows: stride 132 floats (132 mod 32 == 4 -> same bank spread as +4s rotation)
#define BSTRIDE 132
// h_sv parking spot in sC (shorts): above x-stage (shorts 4096..5183); 5248+2047 < 8448
#define HSV2 5248

#define FMA4(acc_, sc_, wv_) do { (acc_).x = fmaf((sc_),(wv_).x,(acc_).x); \
                                  (acc_).y = fmaf((sc_),(wv_).y,(acc_).y); \
                                  (acc_).z = fmaf((sc_),(wv_).z,(acc_).z); \
                                  (acc_).w = fmaf((sc_),(wv_).w,(acc_).w); } while(0)
#define MAX4(mm_, bb_)       do { (mm_).x = fmaxf((mm_).x,(bb_).x); \
                                  (mm_).y = fmaxf((mm_).y,(bb_).y); \
                                  (mm_).z = fmaxf((mm_).z,(bb_).z); \
                                  (mm_).w = fmaxf((mm_).w,(bb_).w); } while(0)

#define MFMA1(acc_, A_, B_) \
    acc_ = __builtin_amdgcn_mfma_f32_16x16x32_bf16((A_), (B_), (acc_), 0, 0, 0)

// Manual RNE (kept for prep_pack so the weight plane is bit-identical to prior rounds)
__device__ __forceinline__ unsigned short bf16_of(float v) {
    unsigned u = __float_as_uint(v);
    u = u + 0x7FFFu + ((u >> 16) & 1u);   // RNE
    return (unsigned short)(u >> 16);
}
__device__ __forceinline__ float f32_of(unsigned short h) {
    return __uint_as_float((unsigned)h << 16);
}
// HW RNE pack: v_cvt_pk_bf16_f32. Bit-identical to bf16_of for finite values.
__device__ __forceinline__ unsigned cvt_pk2(float lo, float hi) {
    unsigned r;
    asm("v_cvt_pk_bf16_f32 %0, %1, %2" : "=v"(r) : "v"(lo), "v"(hi));
    return r;
}
__device__ __forceinline__ unsigned short bf16s(float v) {
    return (unsigned short)cvt_pk2(v, v);
}

// prep: RNE bf16 single plane of 6 matrices, packed in B-fragment order.
// matrices: 0=W_trk2 1=W_sv2 2=Wc1_bot 3=Wd1 4=Wd2 5=Wc2_bot
__global__ void prep_pack(const float* __restrict__ Wtrk2, const float* __restrict__ Wsv2,
                          const float* __restrict__ Wc1,   const float* __restrict__ Wc2,
                          unsigned short* __restrict__ wsu) {
    const int o = blockIdx.x * 256 + threadIdx.x;
    if (o >= 6 * 16384) return;
    const int m = o >> 14, pos = o & 16383;
    const int j = pos & 7, lane = (pos >> 3) & 63, tile = pos >> 9;
    const int ks = tile >> 3, ni = tile & 7;
    const int d = ks * 32 + (lane >> 4) * 8 + j;
    const int c = ni * 16 + (lane & 15);
    const int e = d * 128 + c;
    float v;
    switch (m) {
        case 0: v = Wtrk2[e]; break;
        case 1: v = Wsv2[e]; break;
        case 2: v = Wc1[16384 + e]; break;
        case 3: v = Wc1[e] - Wc1[16384 + e]; break;
        case 4: v = Wc2[e] - Wc2[16384 + e]; break;
        default: v = Wc2[16384 + e]; break;
    }
    wsu[m * 16384 + pos] = bf16_of(v);
}

#define LOADB1(B_, m_, pos_) B_ = *(const short8*)(wsu + (m_) * 16384 + (pos_))
#define LDFRAG(buf_, r_, k0_) (*(const short8*)&(buf_)[RB((r_), (k0_))])

// R10 config (69us/dispatch, no spill) + Phase8a merged into Phase6: a1 and a2 share
// the same T A-fragments in one k-loop (each acc chain bit-identical), deleting the
// Phase8a phase, 8 A-frag ds_reads, and one barrier (T's last reader is now Phase7;
// scores2's last reader topk2 -> single post-topk2 barrier covers P8d's overwrites).
__global__ __launch_bounds__(TPB, 6)
void fused_mfma(const float* __restrict__ x_sv,  const float* __restrict__ x_trk,
                const float* __restrict__ W_sv1, const float* __restrict__ b_sv1,
                const float* __restrict__ b_sv2,
                const float* __restrict__ W_trk1,const float* __restrict__ b_trk1,
                const float* __restrict__ b_trk2,
                const float* __restrict__ b_c1,  const float* __restrict__ b_c2,
                const float* __restrict__ W_o1,  const float* __restrict__ b_o1,
                const float* __restrict__ W_o2,  const float* __restrict__ b_o2,
                const float* __restrict__ W_o3,  const float* __restrict__ b_o3,
                const float* __restrict__ W_o4,  const float* __restrict__ b_o4,
                const unsigned short* __restrict__ wsu,
                float* __restrict__ out)
{
    __shared__ __align__(16) char sAraw[16896]; // T bf16 -> bsrc2 rows 0..31 (fp32, stride 132)
    __shared__ __align__(16) char sBraw[16384]; // h bf16 -> scores1 -> f1 bf16 -> idx2+pool+head
    __shared__ __align__(16) char sCraw[16896]; // sv_emb bf16 + svnorms + x stage + h_sv bf16 -> bsrc1(132) -> scores2 -> bsrc2 rows 32..63
    short*    sAh = (short*)sAraw;    float* sAf = (float*)sAraw;
    short*    sBh = (short*)sBraw;    float* sBf = (float*)sBraw;
    unsigned* sBu = (unsigned*)sBraw;
    short*    sCh = (short*)sCraw;    float* sCf = (float*)sCraw;

    const int g    = blockIdx.x;
    const int tid  = threadIdx.x;
    const int c128 = tid & 127;
    const int g4   = tid >> 7;
    const int wv   = tid >> 6;          // wave 0..7
    const int lane = tid & 63;
    const int quad = lane >> 4;
    const int ln   = lane & 15;

    // ---- P0: stage inputs (x_trk floats 2048..2559, x_sv floats 2560..2591)
    sCf[2048 + tid] = x_trk[(size_t)g * 512 + tid];
    if (tid < 32) sCf[2560 + tid] = x_sv[(size_t)g * 32 + tid];
    __syncthreads();

    // ---- P1 (+P3 merged): trk MLP layer 1 -> h bf16 in sBh ; sv MLP layer 1 -> sCh[HSV2+]
    {
        float w[8];
        #pragma unroll
        for (int k = 0; k < 8; k++) w[k] = W_trk1[k * 128 + c128];
        const float b1 = b_trk1[c128];
        #pragma unroll
        for (int i = 0; i < 16; i++) {
            const int r = g4 * 16 + i;
            float xr[8];
            *(float4*)&xr[0] = *(const float4*)&sCf[2048 + r * 8];
            *(float4*)&xr[4] = *(const float4*)&sCf[2048 + r * 8 + 4];
            float acc = b1;
            #pragma unroll
            for (int k = 0; k < 8; k++) acc = fmaf(xr[k], w[k], acc);
            sBh[RB(r, c128)] = bf16s(elu_fast(acc));
        }
        // P3: h_sv rows 0..15 -> sCh[HSV2 + RB] (disjoint from x stage & everything live)
        const float w0 = W_sv1[c128], w1 = W_sv1[128 + c128];
        const float bs1 = b_sv1[c128];
        #pragma unroll
        for (int i = 0; i < 4; i++) {
            const int s = g4 * 4 + i;
            sCh[HSV2 + RB(s, c128)] = bf16s(
                elu_fast(fmaf(sCf[2560 + s * 2 + 1], w1, fmaf(sCf[2560 + s * 2], w0, bs1))));
        }
    }
    __syncthreads();

    // ---- P2 (+P3b merged, MFMA): T = relu(h @ W_trk2 + b) -> sAh bf16 ;
    //      sv_emb = relu(h_sv @ W_sv2 + b) -> sCh rows 0..15 ; col-partial norms -> sCf[1024..1151]
    {
        const int mi = wv >> 1, nb = (wv & 1) * 4;
        const int row = mi * 16 + ln;
        f32x4 acc[4];
        #pragma unroll
        for (int t = 0; t < 4; t++) {
            const float bz = b_trk2[(nb + t) * 16 + ln];
            acc[t] = (f32x4){bz, bz, bz, bz};
        }
        #pragma unroll 2
        for (int ks = 0; ks < 4; ks++) {
            const int k0 = ks * 32 + quad * 8;
            const short8 A = LDFRAG(sBh, row, k0);
            #pragma unroll
            for (int t = 0; t < 4; t++) {
                const int pos = ((ks * 8 + (nb + t)) * 64 + lane) * 8;
                short8 B;
                LOADB1(B, 0, pos);
                MFMA1(acc[t], A, B);
            }
        }
        #pragma unroll
        for (int t = 0; t < 4; t++)
            #pragma unroll
            for (int r = 0; r < 4; r++)
                sAh[RB(mi * 16 + quad * 4 + r, (nb + t) * 16 + ln)] =
                    bf16s(fmaxf(acc[t][r], 0.f));
        // P3b: sv_emb (reads h_sv from sCh[HSV2+], writes sCh rows 0..15 + norms sCf[1024+])
        const int ni = wv;
        const float bz2 = b_sv2[ni * 16 + ln];
        f32x4 accs = (f32x4){bz2, bz2, bz2, bz2};
        #pragma unroll 2
        for (int ks = 0; ks < 4; ks++) {
            const int k0 = ks * 32 + quad * 8;
            const short8 A = *(const short8*)&sCh[HSV2 + RB(ln, k0)];
            const int pos = ((ks * 8 + ni) * 64 + lane) * 8;
            short8 B;
            LOADB1(B, 1, pos);
            MFMA1(accs, A, B);
        }
        #pragma unroll
        for (int r = 0; r < 4; r++) {
            const float v = fmaxf(accs[r], 0.f);
            sCh[RB(quad * 4 + r, ni * 16 + ln)] = bf16s(v);
            float p = v * v;
            #pragma unroll
            for (int o = 1; o <= 8; o <<= 1) p += __shfl_xor(p, o, 16);
            if (ln == 0) sCf[1024 + ni * 16 + quad * 4 + r] = p;
        }
    }
    __syncthreads();

    // ---- B1 (MFMA): bsrc1 = sv @ Wc1_bot -> sCf[1984..] stride 132; P4 (waves 0..3): scores1 -> sBf
    {
        const int ni = wv;
        const bool doP4 = (wv < 4);
        f32x4 accB = (f32x4){0.f, 0.f, 0.f, 0.f};
        f32x4 accS = (f32x4){0.f, 0.f, 0.f, 0.f};
        #pragma unroll 2
        for (int ks = 0; ks < 4; ks++) {
            const int k0 = ks * 32 + quad * 8;
            const short8 S = LDFRAG(sCh, ln, k0);
            const int pos = ((ks * 8 + ni) * 64 + lane) * 8;
            short8 B;
            LOADB1(B, 2, pos);
            MFMA1(accB, S, B);
            if (doP4) {
                const short8 T = LDFRAG(sAh, wv * 16 + ln, k0);
                MFMA1(accS, T, S);
            }
        }
        #pragma unroll
        for (int r = 0; r < 4; r++)
            sCf[1984 + (quad * 4 + r) * BSTRIDE + ni * 16 + ln] = accB[r];
        if (doP4) {
            float nsv = 0.f;
            #pragma unroll
            for (int p = 0; p < 8; p++) nsv += sCf[1024 + p * 16 + ln];
            #pragma unroll
            for (int r = 0; r < 4; r++)
                sBf[(wv * 16 + quad * 4 + r) * 17 + ln] = fmaf(-2.f, accS[r], nsv);
        }
    }
    __syncthreads();

    // ---- topk1: top-8 of 16 (shfl) -> packs sBu[1088+q]
    {
        const int q  = tid >> 3;
        const int s0 = tid & 7;
        float sc0 = sBf[q * 17 + s0];
        float sc1 = sBf[q * 17 + s0 + 8];
        unsigned pack1 = 0u;
        #pragma unroll
        for (int r = 0; r < 8; r++) {
            float bv = sc0; int bs = s0;
            if (sc1 < bv) { bv = sc1; bs = s0 + 8; }
            #pragma unroll
            for (int o = 1; o <= 4; o <<= 1) {
                const float ov = __shfl_xor(bv, o, 8);
                const int   os = __shfl_xor(bs, o, 8);
                if (ov < bv || (ov == bv && os < bs)) { bv = ov; bs = os; }
            }
            pack1 |= (unsigned)bs << (4 * r);
            if (bs == s0)     sc0 = INF_F;
            if (bs == s0 + 8) sc1 = INF_F;
        }
        if (s0 == 0) sBu[1088 + q] = pack1;
    }
    __syncthreads();

    // ---- Phase6 (+Phase8a merged, MFMA): a1 = T @ Wd1 + b1 AND a2 = T @ Wd2 + b2
    //      (shared A-frags, per-acc chains bit-identical); a2 -> 8 packed-bf16 regs;
    //      f1 = elu(a1 + max bsrc1[idx]) -> sBh bf16; f1-norm halves -> sCf[0..127]
    unsigned a2p[8];
    {
        const int mi = wv >> 1, nb = (wv & 1) * 4;
        const int row = mi * 16 + ln;
        f32x4 a1acc[4], a2acc[4];
        #pragma unroll
        for (int t = 0; t < 4; t++) {
            const float bz1 = b_c1[(nb + t) * 16 + ln];
            const float bz2 = b_c2[(nb + t) * 16 + ln];
            a1acc[t] = (f32x4){bz1, bz1, bz1, bz1};
            a2acc[t] = (f32x4){bz2, bz2, bz2, bz2};
        }
        #pragma unroll 2
        for (int ks = 0; ks < 4; ks++) {
            const int k0 = ks * 32 + quad * 8;
            const short8 A = LDFRAG(sAh, row, k0);
            #pragma unroll
            for (int t = 0; t < 4; t++) {
                const int pos = ((ks * 8 + (nb + t)) * 64 + lane) * 8;
                short8 B1, B2;
                LOADB1(B1, 3, pos);
                LOADB1(B2, 4, pos);
                MFMA1(a1acc[t], A, B1);
                MFMA1(a2acc[t], A, B2);
            }
        }
        #pragma unroll
        for (int t = 0; t < 4; t++) {
            a2p[2 * t]     = cvt_pk2(a2acc[t][0], a2acc[t][1]);
            a2p[2 * t + 1] = cvt_pk2(a2acc[t][2], a2acc[t][3]);
        }
        // read packs into regs BEFORE barrier (f1 writes overwrite sBu[1088..])
        unsigned pk[4];
        #pragma unroll
        for (int r = 0; r < 4; r++) pk[r] = sBu[1088 + mi * 16 + quad * 4 + r];
        __syncthreads();
        float np[4] = {0.f, 0.f, 0.f, 0.f};
        const int ccb = nb * 16 + ln;   // col for t: ccb + 16*t
        const float* b1base = &sCf[1984 + ccb];
        #pragma unroll
        for (int r = 0; r < 4; r++) {
            float mx0 = -INF_F, mx1 = -INF_F, mx2 = -INF_F, mx3 = -INF_F;
            #pragma unroll
            for (int j = 0; j < 8; j++) {
                const int s = (int)((pk[r] >> (4 * j)) & 15u);
                const float* rp = b1base + s * BSTRIDE;
                mx0 = fmaxf(mx0, rp[0]);
                mx1 = fmaxf(mx1, rp[16]);
                mx2 = fmaxf(mx2, rp[32]);
                mx3 = fmaxf(mx3, rp[48]);
            }
            const float mxa[4] = {mx0, mx1, mx2, mx3};
            #pragma unroll
            for (int t = 0; t < 4; t++) {
                const float f = elu_fast(a1acc[t][r] + mxa[t]);
                sBh[RB(mi * 16 + quad * 4 + r, ccb + 16 * t)] = bf16s(f);
                np[r] = fmaf(f, f, np[r]);
            }
        }
        #pragma unroll
        for (int r = 0; r < 4; r++) {
            #pragma unroll
            for (int o = 1; o <= 8; o <<= 1) np[r] += __shfl_xor(np[r], o, 16);
            if (ln == 0) sCf[(wv & 1) * 64 + mi * 16 + quad * 4 + r] = np[r];
        }
    }
    __syncthreads();

    // ---- Phase7 (MFMA): scores2[q][s] = n_s - 2 T_q . f1_s -> sCf[q*64+s]
    {
        const int mi = wv >> 1, nia = (wv & 1) * 2;
        const int row = mi * 16 + ln;
        float ns[2];
        #pragma unroll
        for (int u = 0; u < 2; u++) {
            const int s = (nia + u) * 16 + ln;
            ns[u] = sCf[s] + sCf[64 + s];
        }
        __syncthreads();   // norms read before scores overwrite sCf
        f32x4 acc[2];
        acc[0] = (f32x4){0.f, 0.f, 0.f, 0.f};
        acc[1] = (f32x4){0.f, 0.f, 0.f, 0.f};
        #pragma unroll 2
        for (int ks = 0; ks < 4; ks++) {
            const int k0 = ks * 32 + quad * 8;
            const short8 A = LDFRAG(sAh, row, k0);
            #pragma unroll
            for (int u = 0; u < 2; u++) {
                const short8 Bf = LDFRAG(sBh, (nia + u) * 16 + ln, k0);
                MFMA1(acc[u], A, Bf);
            }
        }
        #pragma unroll
        for (int u = 0; u < 2; u++) {
            const int s = (nia + u) * 16 + ln;
            #pragma unroll
            for (int r = 0; r < 4; r++)
                sCf[(mi * 16 + quad * 4 + r) * 64 + s] = fmaf(-2.f, acc[u][r], ns[u]);
        }
    }
    __syncthreads();

    // ---- topk2: top-8 of 64 (shfl) ; lo2/hi2 kept in regs until post-P8d handoff
    unsigned lo2, hi2;
    {
        const int q = tid >> 3;
        const int j = tid & 7;
        float v[8];
        *(float4*)&v[0] = *(const float4*)&sCf[q * 64 + 8 * j];
        *(float4*)&v[4] = *(const float4*)&sCf[q * 64 + 8 * j + 4];
        lo2 = 0u; hi2 = 0u;
        #pragma unroll
        for (int r = 0; r < 8; r++) {
            float bv = v[0]; int bs = 8 * j;
            #pragma unroll
            for (int t = 1; t < 8; t++)
                if (v[t] < bv) { bv = v[t]; bs = 8 * j + t; }
            #pragma unroll
            for (int o = 1; o <= 4; o <<= 1) {
                const float ov = __shfl_xor(bv, o, 8);
                const int   os = __shfl_xor(bs, o, 8);
                if (ov < bv || (ov == bv && os < bs)) { bv = ov; bs = os; }
            }
            if (r < 4) lo2 |= (unsigned)bs << (8 * r);
            else       hi2 |= (unsigned)bs << (8 * (r - 4));
            #pragma unroll
            for (int t = 0; t < 8; t++)
                if (bs == 8 * j + t) v[t] = INF_F;
        }
    }
    __syncthreads();   // scores2 reads done (sCf) AND T dead since Phase7 (sAf) -> P8d may write both

    // ---- P8d (MFMA): bsrc2 = f1 @ Wc2_bot, fp32 stride 132, rows 0..31 -> sAf, 32..63 -> sCf
    {
        const int mi = wv >> 1, nb = (wv & 1) * 4;
        const int row = mi * 16 + ln;
        f32x4 acc[4];
        #pragma unroll
        for (int t = 0; t < 4; t++) acc[t] = (f32x4){0.f, 0.f, 0.f, 0.f};
        #pragma unroll 2
        for (int ks = 0; ks < 4; ks++) {
            const int k0 = ks * 32 + quad * 8;
            const short8 A = LDFRAG(sBh, row, k0);
            #pragma unroll
            for (int t = 0; t < 4; t++) {
                const int pos = ((ks * 8 + (nb + t)) * 64 + lane) * 8;
                short8 B;
                LOADB1(B, 5, pos);
                MFMA1(acc[t], A, B);
            }
        }
        float* bp = (mi < 2) ? sAf : sCf;   // wave-uniform
        const int ccb = nb * 16 + ln;
        #pragma unroll
        for (int t = 0; t < 4; t++)
            #pragma unroll
            for (int r = 0; r < 4; r++) {
                const int rr = mi * 16 + quad * 4 + r;
                bp[(rr & 31) * BSTRIDE + ccb + 16 * t] = acc[t][r];
            }
    }
    __syncthreads();   // f1 now dead -> sB free for idx2 handoff

    // ---- idx2 handoff -> sBu[1024 + 2q] (dead f1 space)
    if ((tid & 7) == 0) {
        const int q = tid >> 3;
        sBu[1024 + 2 * q]     = lo2;
        sBu[1024 + 2 * q + 1] = hi2;
    }
    __syncthreads();

    // ---- Phase9: f2 = elu(a2 + max bsrc2[idx]) ; pool -> sBf[0..511]
    {
        const int mi = wv >> 1, nb = (wv & 1) * 4;
        float ps[4] = {0.f, 0.f, 0.f, 0.f};
        const int ccb = nb * 16 + ln;
        const float* bA = &sAf[ccb];
        const float* bC = &sCf[ccb];
        #pragma unroll
        for (int r = 0; r < 4; r++) {
            const int rr = mi * 16 + quad * 4 + r;
            const unsigned plo = sBu[1024 + 2 * rr];
            const unsigned phi = sBu[1024 + 2 * rr + 1];
            float mx0 = -INF_F, mx1 = -INF_F, mx2 = -INF_F, mx3 = -INF_F;
            #pragma unroll
            for (int j = 0; j < 8; j++) {
                const int s = (int)(((j < 4) ? (plo >> (8 * j))
                                             : (phi >> (8 * (j - 4)))) & 63u);
                const float* rp = ((s < 32) ? bA : bC) + (s & 31) * BSTRIDE;
                mx0 = fmaxf(mx0, rp[0]);
                mx1 = fmaxf(mx1, rp[16]);
                mx2 = fmaxf(mx2, rp[32]);
                mx3 = fmaxf(mx3, rp[48]);
            }
            const float mxa[4] = {mx0, mx1, mx2, mx3};
            #pragma unroll
            for (int t = 0; t < 4; t++) {
                const unsigned u = a2p[2 * t + (r >> 1)];
                const float a2v = __uint_as_float((r & 1) ? (u & 0xFFFF0000u) : (u << 16));
                ps[t] += elu_fast(a2v + mxa[t]);
            }
        }
        #pragma unroll
        for (int t = 0; t < 4; t++) {
            ps[t] += __shfl_xor(ps[t], 16, 64);
            ps[t] += __shfl_xor(ps[t], 32, 64);
        }
        if (lane < 16)
            #pragma unroll
            for (int t = 0; t < 4; t++)
                sBf[mi * 128 + (nb + t) * 16 + lane] = ps[t];
    }
    __syncthreads();

    // ---- Head
    if (tid < 128) {
        const float p = (sBf[tid] + sBf[128 + tid] + sBf[256 + tid] + sBf[384 + tid]) * (1.f / 64.f);
        sBf[512 + tid] = p;
    }
    __syncthreads();
    if (tid < 64) {
        float acc = b_o1[tid];
        for (int d = 0; d < 128; d++) acc = fmaf(sBf[512 + d], W_o1[d * 64 + tid], acc);
        sBf[640 + tid] = elu_fast(acc);
    }
    __syncthreads();
    if (tid < 32) {
        float acc = b_o2[tid];
        for (int d = 0; d < 64; d++) acc = fmaf(sBf[640 + d], W_o2[d * 32 + tid], acc);
        sBf[704 + tid] = elu_fast(acc);
    }
    __syncthreads();
    if (tid < 4) {
        float acc = b_o3[tid];
        for (int d = 0; d < 32; d++) acc = fmaf(sBf[704 + d], W_o3[d * 4 + tid], acc);
        sBf[736 + tid] = elu_fast(acc);
    }
    __syncthreads();
    if (tid == 0) {
        float acc = b_o4[0];
        #pragma unroll
        for (int d = 0; d < 4; d++) acc = fmaf(sBf[736 + d], W_o4[d], acc);
        out[g] = acc;
        out[G_ + g] = (float)g;
    }
}

// ================= vector fallback (round-4 kernel, inline weight diffs) =================
#define ROTV(r, d)    ((r)*128 + (((d) + 4*(r)) & 127))
#define BS1V(s, c)    (2048 + (s)*128 + (((c) + 4*(s)) & 127))
__global__ __launch_bounds__(TPB, 2)
void fused_vec(const float* __restrict__ x_sv,  const float* __restrict__ x_trk,
               const float* __restrict__ W_sv1, const float* __restrict__ b_sv1,
               const float* __restrict__ W_sv2, const float* __restrict__ b_sv2,
               const float* __restrict__ W_trk1,const float* __restrict__ b_trk1,
               const float* __restrict__ W_trk2,const float* __restrict__ b_trk2,
               const float* __restrict__ W_c1,  const float* __restrict__ b_c1,
               const float* __restrict__ W_c2,  const float* __restrict__ b_c2,
               const float* __restrict__ W_o1,  const float* __restrict__ b_o1,
               const float* __restrict__ W_o2,  const float* __restrict__ b_o2,
               const float* __restrict__ W_o3,  const float* __restrict__ b_o3,
               const float* __restrict__ W_o4,  const float* __restrict__ b_o4,
               float* __restrict__ out)
{
    __shared__ float sA[8192];
    __shared__ float sB[8192];
    __shared__ float sC[4096];
    const int g    = blockIdx.x;
    const int tid  = threadIdx.x;
    const int c128 = tid & 127;
    const int g4   = tid >> 7;
    const int cq   = tid & 31;
    const int c0   = cq * 4;
    const int rg   = tid >> 5;
    const int lane_hi = tid & 32;

    sC[2048 + tid] = x_trk[(size_t)g * 512 + tid];
    if (tid < 32) sC[2560 + tid] = x_sv[(size_t)g * 32 + tid];
    __syncthreads();
    {
        float w[8];
        #pragma unroll
        for (int k = 0; k < 8; k++) w[k] = W_trk1[k * 128 + c128];
        const float b1 = b_trk1[c128];
        #pragma unroll
        for (int i = 0; i < 16; i++) {
            const int r = g4 * 16 + i;
            float acc = b1;
            #pragma unroll
            for (int k = 0; k < 8; k++) acc = fmaf(sC[2048 + r * 8 + k], w[k], acc);
            sB[r * 128 + c128] = elu_ref(acc);
        }
    }
    __syncthreads();
    {
        const int r0 = rg * 4;
        float4 acc[4];
        const float4 bz = *(const float4*)&b_trk2[c0];
        #pragma unroll
        for (int i = 0; i < 4; i++) acc[i] = bz;
        for (int d0 = 0; d0 < 128; d0 += 4) {
            const float4 w0 = *(const float4*)&W_trk2[(d0 + 0) * 128 + c0];
            const float4 w1 = *(const float4*)&W_trk2[(d0 + 1) * 128 + c0];
            const float4 w2 = *(const float4*)&W_trk2[(d0 + 2) * 128 + c0];
            const float4 w3 = *(const float4*)&W_trk2[(d0 + 3) * 128 + c0];
            #pragma unroll
            for (int i = 0; i < 4; i++) {
                const float4 h = *(const float4*)&sB[(r0 + i) * 128 + d0];
                FMA4(acc[i], h.x, w0); FMA4(acc[i], h.y, w1);
                FMA4(acc[i], h.z, w2); FMA4(acc[i], h.w, w3);
            }
        }
        #pragma unroll
        for (int i = 0; i < 4; i++) {
            float4 r;
            r.x = fmaxf(acc[i].x, 0.f); r.y = fmaxf(acc[i].y, 0.f);
            r.z = fmaxf(acc[i].z, 0.f); r.w = fmaxf(acc[i].w, 0.f);
            *(float4*)&sA[ROTV(r0 + i, c0)] = r;
        }
    }
    __syncthreads();
    {
        const float w0 = W_sv1[c128], w1 = W_sv1[128 + c128];
        const float b1 = b_sv1[c128];
        #pragma unroll
        for (int i = 0; i < 4; i++) {
            const int s = g4 * 4 + i;
            sB[s * 128 + c128] =
                elu_ref(fmaf(sC[2560 + s * 2 + 1], w1, fmaf(sC[2560 + s * 2], w0, b1)));
        }
    }
    __syncthreads();
    {
        const int s = rg;
        float4 acc = *(const float4*)&b_sv2[c0];
        for (int d0 = 0; d0 < 128; d0 += 4) {
            const float4 w0 = *(const float4*)&W_sv2[(d0 + 0) * 128 + c0];
            const float4 w1 = *(const float4*)&W_sv2[(d0 + 1) * 128 + c0];
            const float4 w2 = *(const float4*)&W_sv2[(d0 + 2) * 128 + c0];
            const float4 w3 = *(const float4*)&W_sv2[(d0 + 3) * 128 + c0];
            const float4 h = *(const float4*)&sB[s * 128 + d0];
            FMA4(acc, h.x, w0); FMA4(acc, h.y, w1);
            FMA4(acc, h.z, w2); FMA4(acc, h.w, w3);
        }
        float4 r;
        r.x = fmaxf(acc.x, 0.f); r.y = fmaxf(acc.y, 0.f);
        r.z = fmaxf(acc.z, 0.f); r.w = fmaxf(acc.w, 0.f);
        *(float4*)&sC[ROTV(s, c0)] = r;
    }
    __syncthreads();
    unsigned pack1;
    {
        {
            const int s = rg;
            float4 acc = {0.f, 0.f, 0.f, 0.f};
            for (int d0 = 0; d0 < 128; d0 += 4) {
                const float4 e  = *(const float4*)&sC[ROTV(s, d0)];
                const float4 w0 = *(const float4*)&W_c1[(128 + d0 + 0) * 128 + c0];
                const float4 w1 = *(const float4*)&W_c1[(128 + d0 + 1) * 128 + c0];
                const float4 w2 = *(const float4*)&W_c1[(128 + d0 + 2) * 128 + c0];
                const float4 w3 = *(const float4*)&W_c1[(128 + d0 + 3) * 128 + c0];
                FMA4(acc, e.x, w0); FMA4(acc, e.y, w1);
                FMA4(acc, e.z, w2); FMA4(acc, e.w, w3);
            }
            *(float4*)&sC[BS1V(s, c0)] = acc;
        }
        const int q  = tid >> 3;
        const int s0 = tid & 7;
        float d0a = 0.f, d1a = 0.f, n0 = 0.f, n1 = 0.f;
        for (int d0 = 0; d0 < 128; d0 += 4) {
            const float4 t  = *(const float4*)&sA[ROTV(q, d0)];
            const float4 v0 = *(const float4*)&sC[ROTV(s0, d0)];
            const float4 v1 = *(const float4*)&sC[ROTV(s0 + 8, d0)];
            d0a += t.x * v0.x + t.y * v0.y + t.z * v0.z + t.w * v0.w;
            d1a += t.x * v1.x + t.y * v1.y + t.z * v1.z + t.w * v1.w;
            n0  += v0.x * v0.x + v0.y * v0.y + v0.z * v0.z + v0.w * v0.w;
            n1  += v1.x * v1.x + v1.y * v1.y + v1.z * v1.z + v1.w * v1.w;
        }
        float sc0 = fmaf(-2.f, d0a, n0);
        float sc1 = fmaf(-2.f, d1a, n1);
        pack1 = 0u;
        #pragma unroll
        for (int r = 0; r < 8; r++) {
            float bv = sc0; int bs = s0;
            if (sc1 < bv) { bv = sc1; bs = s0 + 8; }
            #pragma unroll
            for (int o = 1; o <= 4; o <<= 1) {
                const float ov = __shfl_xor(bv, o, 8);
                const int   os = __shfl_xor(bs, o, 8);
                if (ov < bv || (ov == bv && os < bs)) { bv = ov; bs = os; }
            }
            pack1 |= (unsigned)bs << (4 * r);
            if (bs == s0)     sc0 = INF_F;
            if (bs == s0 + 8) sc1 = INF_F;
        }
    }
    __syncthreads();
    float4 a2v[4];
    {
        const int q0 = rg * 4;
        float4 a1[4];
        const float4 bc1 = *(const float4*)&b_c1[c0];
        const float4 bc2 = *(const float4*)&b_c2[c0];
        #pragma unroll
        for (int i = 0; i < 4; i++) { a1[i] = bc1; a2v[i] = bc2; }
        for (int d0 = 0; d0 < 128; d0 += 4) {
            float4 t[4];
            #pragma unroll
            for (int i = 0; i < 4; i++) t[i] = *(const float4*)&sA[ROTV(q0 + i, d0)];
            #pragma unroll
            for (int dj = 0; dj < 4; dj++) {
                float4 wv;
                const float4 wa = *(const float4*)&W_c1[(d0 + dj) * 128 + c0];
                const float4 wb = *(const float4*)&W_c1[(128 + d0 + dj) * 128 + c0];
                wv.x = wa.x - wb.x; wv.y = wa.y - wb.y;
                wv.z = wa.z - wb.z; wv.w = wa.w - wb.w;
                FMA4(a1[0], ((const float*)&t[0])[dj], wv);
                FMA4(a1[1], ((const float*)&t[1])[dj], wv);
                FMA4(a1[2], ((const float*)&t[2])[dj], wv);
                FMA4(a1[3], ((const float*)&t[3])[dj], wv);
            }
            #pragma unroll
            for (int dj = 0; dj < 4; dj++) {
                float4 wv;
                const float4 wa = *(const float4*)&W_c2[(d0 + dj) * 128 + c0];
                const float4 wb = *(const float4*)&W_c2[(128 + d0 + dj) * 128 + c0];
                wv.x = wa.x - wb.x; wv.y = wa.y - wb.y;
                wv.z = wa.z - wb.z; wv.w = wa.w - wb.w;
                FMA4(a2v[0], ((const float*)&t[0])[dj], wv);
                FMA4(a2v[1], ((const float*)&t[1])[dj], wv);
                FMA4(a2v[2], ((const float*)&t[2])[dj], wv);
                FMA4(a2v[3], ((const float*)&t[3])[dj], wv);
            }
        }
        #pragma unroll
        for (int i = 0; i < 4; i++) {
            const int q = q0 + i;
            const unsigned pk = __shfl(pack1, 8 * i + lane_hi);
            float4 m = {-INF_F, -INF_F, -INF_F, -INF_F};
            #pragma unroll
            for (int j = 0; j < 8; j++) {
                const int s = (int)((pk >> (4 * j)) & 15u);
                const float4 b = *(const float4*)&sC[BS1V(s, c0)];
                MAX4(m, b);
            }
            float4 f;
            f.x = elu_ref(a1[i].x + m.x); f.y = elu_ref(a1[i].y + m.y);
            f.z = elu_ref(a1[i].z + m.z); f.w = elu_ref(a1[i].w + m.w);
            *(float4*)&sB[ROTV(q, c0)] = f;
        }
    }
    __syncthreads();
    {
        const int s  = tid & 63;
        const int q0 = (tid >> 6) * 8;
        float acc[8];
        #pragma unroll
        for (int i = 0; i < 8; i++) acc[i] = 0.f;
        float nrm = 0.f;
        for (int d0 = 0; d0 < 128; d0 += 4) {
            const float4 f = *(const float4*)&sB[ROTV(s, d0)];
            nrm = fmaf(f.x, f.x, nrm); nrm = fmaf(f.y, f.y, nrm);
            nrm = fmaf(f.z, f.z, nrm); nrm = fmaf(f.w, f.w, nrm);
            #pragma unroll
            for (int i = 0; i < 8; i++) {
                const float4 t = *(const float4*)&sA[ROTV(q0 + i, d0)];
                acc[i] = fmaf(t.x, f.x, acc[i]); acc[i] = fmaf(t.y, f.y, acc[i]);
                acc[i] = fmaf(t.z, f.z, acc[i]); acc[i] = fmaf(t.w, f.w, acc[i]);
            }
        }
        #pragma unroll
        for (int i = 0; i < 8; i++)
            sC[(q0 + i) * 64 + s] = fmaf(-2.f, acc[i], nrm);
    }
    __syncthreads();
    unsigned lo2, hi2;
    {
        const int q = tid >> 3;
        const int j = tid & 7;
        float v[8];
        *(float4*)&v[0] = *(const float4*)&sC[q * 64 + 8 * j];
        *(float4*)&v[4] = *(const float4*)&sC[q * 64 + 8 * j + 4];
        lo2 = 0u; hi2 = 0u;
        #pragma unroll
        for (int r = 0; r < 8; r++) {
            float bv = v[0]; int bs = 8 * j;
            #pragma unroll
            for (int t = 1; t < 8; t++)
                if (v[t] < bv) { bv = v[t]; bs = 8 * j + t; }
            #pragma unroll
            for (int o = 1; o <= 4; o <<= 1) {
                const float ov = __shfl_xor(bv, o, 8);
                const int   os = __shfl_xor(bs, o, 8);
                if (ov < bv || (ov == bv && os < bs)) { bv = ov; bs = os; }
            }
            if (r < 4) lo2 |= (unsigned)bs << (8 * r);
            else       hi2 |= (unsigned)bs << (8 * (r - 4));
            #pragma unroll
            for (int t = 0; t < 8; t++)
                if (bs == 8 * j + t) v[t] = INF_F;
        }
        const int r0 = rg * 4;
        float4 acc[4];
        #pragma unroll
        for (int i = 0; i < 4; i++) acc[i] = make_float4(0.f, 0.f, 0.f, 0.f);
        for (int d0 = 0; d0 < 128; d0 += 4) {
            const float4 w0 = *(const float4*)&W_c2[(128 + d0 + 0) * 128 + c0];
            const float4 w1 = *(const float4*)&W_c2[(128 + d0 + 1) * 128 + c0];
            const float4 w2 = *(const float4*)&W_c2[(128 + d0 + 2) * 128 + c0];
            const float4 w3 = *(const float4*)&W_c2[(128 + d0 + 3) * 128 + c0];
            #pragma unroll
            for (int i = 0; i < 4; i++) {
                const float4 f = *(const float4*)&sB[ROTV(r0 + i, d0)];
                FMA4(acc[i], f.x, w0); FMA4(acc[i], f.y, w1);
                FMA4(acc[i], f.z, w2); FMA4(acc[i], f.w, w3);
            }
        }
        #pragma unroll
        for (int i = 0; i < 4; i++)
            *(float4*)&sA[ROTV(r0 + i, c0)] = acc[i];
    }
    __syncthreads();
    {
        const int q0 = rg * 4;
        float4 ps = {0.f, 0.f, 0.f, 0.f};
        #pragma unroll
        for (int i = 0; i < 4; i++) {
            const unsigned plo = __shfl(lo2, 8 * i + lane_hi);
            const unsigned phi = __shfl(hi2, 8 * i + lane_hi);
            float4 m = {-INF_F, -INF_F, -INF_F, -INF_F};
            #pragma unroll
            for (int j = 0; j < 8; j++) {
                const int s = (int)(((j < 4) ? (plo >> (8 * j)) : (phi >> (8 * (j - 4)))) & 63u);
                const float4 b = *(const float4*)&sA[ROTV(s, c0)];
                MAX4(m, b);
            }
            ps.x += elu_ref(a2v[i].x + m.x); ps.y += elu_ref(a2v[i].y + m.y);
            ps.z += elu_ref(a2v[i].z + m.z); ps.w += elu_ref(a2v[i].w + m.w);
        }
        *(float4*)&sB[rg * 128 + c0] = ps;
    }
    __syncthreads();
    if (tid < 128) {
        float p = 0.f;
        #pragma unroll
        for (int t = 0; t < 16; t++) p += sB[t * 128 + tid];
        sB[2048 + tid] = p * (1.f / 64.f);
    }
    __syncthreads();
    if (tid < 64) {
        float acc = b_o1[tid];
        for (int d = 0; d < 128; d++) acc = fmaf(sB[2048 + d], W_o1[d * 64 + tid], acc);
        sB[2176 + tid] = elu_ref(acc);
    }
    __syncthreads();
    if (tid < 32) {
        float acc = b_o2[tid];
        for (int d = 0; d < 64; d++) acc = fmaf(sB[2176 + d], W_o2[d * 32 + tid], acc);
        sB[2240 + tid] = elu_ref(acc);
    }
    __syncthreads();
    if (tid < 4) {
        float acc = b_o3[tid];
        for (int d = 0; d < 32; d++) acc = fmaf(sB[2240 + d], W_o3[d * 4 + tid], acc);
        sB[2272 + tid] = elu_ref(acc);
    }
    __syncthreads();
    if (tid == 0) {
        float acc = b_o4[0];
        #pragma unroll
        for (int d = 0; d < 4; d++) acc = fmaf(sB[2272 + d], W_o4[d], acc);
        out[g] = acc;
        out[G_ + g] = (float)g;
    }
}

extern "C" void kernel_launch(void* const* d_in, const int* in_sizes, int n_in,
                              void* d_out, int out_size, void* d_ws, size_t ws_size,
                              hipStream_t stream) {
    const float* x_sv   = (const float*)d_in[0];
    const float* x_trk  = (const float*)d_in[1];
    const float* W_sv1  = (const float*)d_in[2];
    const float* b_sv1  = (const float*)d_in[3];
    const float* W_sv2  = (const float*)d_in[4];
    const float* b_sv2  = (const float*)d_in[5];
    const float* W_trk1 = (const float*)d_in[6];
    const float* b_trk1 = (const float*)d_in[7];
    const float* W_trk2 = (const float*)d_in[8];
    const float* b_trk2 = (const float*)d_in[9];
    const float* W_c1   = (const float*)d_in[10];
    const float* b_c1   = (const float*)d_in[11];
    const float* W_c2   = (const float*)d_in[12];
    const float* b_c2   = (const float*)d_in[13];
    const float* W_o1   = (const float*)d_in[14];
    const float* b_o1   = (const float*)d_in[15];
    const float* W_o2   = (const float*)d_in[16];
    const float* b_o2   = (const float*)d_in[17];
    const float* W_o3   = (const float*)d_in[18];
    const float* b_o3   = (const float*)d_in[19];
    const float* W_o4   = (const float*)d_in[20];
    const float* b_o4   = (const float*)d_in[21];
    float* out = (float*)d_out;

    const size_t WS_NEED = (size_t)6 * 16384 * sizeof(unsigned short); // 192 KB
    if (ws_size >= WS_NEED && d_ws != nullptr) {
        unsigned short* wsu = (unsigned short*)d_ws;
        prep_pack<<<384, 256, 0, stream>>>(W_trk2, W_sv2, W_c1, W_c2, wsu);
        fused_mfma<<<G_, TPB, 0, stream>>>(x_sv, x_trk, W_sv1, b_sv1, b_sv2,
                                           W_trk1, b_trk1, b_trk2, b_c1, b_c2,
                                           W_o1, b_o1, W_o2, b_o2, W_o3, b_o3,
                                           W_o4, b_o4, wsu, out);
    } else {
        fused_vec<<<G_, TPB, 0, stream>>>(x_sv, x_trk, W_sv1, b_sv1, W_sv2, b_sv2,
                                          W_trk1, b_trk1, W_trk2, b_trk2,
                                          W_c1, b_c1, W_c2, b_c2,
                                          W_o1, b_o1, W_o2, b_o2, W_o3, b_o3,
                                          W_o4, b_o4, out);
    }
}

// Round 12
// 162.735 us; speedup vs baseline: 1.0635x; 1.0635x over previous
//
#include <hip/hip_runtime.h>

#define G_    1024
#define TPB   512
#define INF_F 3.4e38f

typedef __attribute__((ext_vector_type(8))) short short8;
typedef __attribute__((ext_vector_type(4))) float f32x4;

__device__ __forceinline__ float elu_fast(float x) { return x > 0.f ? x : __expf(x) - 1.f; }
__device__ __forceinline__ float elu_ref(float x)  { return x > 0.f ? x : expm1f(x); }

// bf16 tile rows: rotation by 8 shorts (16B) keeps short8 frag loads aligned; 2-way banks
#define RB(r, c)     ((r)*128 + (((c) + 8*(r)) & 127))
// bsrc rows: stride 132 floats (132 mod 32 == 4 -> same bank spread as +4s rotation),
// no wrap -> immediate-offset gather reads (ds_read2-friendly)
#define BSTRIDE 132
// h_sv parking spot in sC (shorts): above x-stage (shorts 4096..5183); 5248+2047 < 8448
#define HSV2 5248

#define FMA4(acc_, sc_, wv_) do { (acc_).x = fmaf((sc_),(wv_).x,(acc_).x); \
                                  (acc_).y = fmaf((sc_),(wv_).y,(acc_).y); \
                                  (acc_).z = fmaf((sc_),(wv_).z,(acc_).z); \
                                  (acc_).w = fmaf((sc_),(wv_).w,(acc_).w); } while(0)
#define MAX4(mm_, bb_)       do { (mm_).x = fmaxf((mm_).x,(bb_).x); \
                                  (mm_).y = fmaxf((mm_).y,(bb_).y); \
                                  (mm_).z = fmaxf((mm_).z,(bb_).z); \
                                  (mm_).w = fmaxf((mm_).w,(bb_).w); } while(0)

#define MFMA1(acc_, A_, B_) \
    acc_ = __builtin_amdgcn_mfma_f32_16x16x32_bf16((A_), (B_), (acc_), 0, 0, 0)

// Manual RNE (kept for prep_pack so the weight plane is bit-identical to prior rounds)
__device__ __forceinline__ unsigned short bf16_of(float v) {
    unsigned u = __float_as_uint(v);
    u = u + 0x7FFFu + ((u >> 16) & 1u);   // RNE
    return (unsigned short)(u >> 16);
}
__device__ __forceinline__ float f32_of(unsigned short h) {
    return __uint_as_float((unsigned)h << 16);
}
// HW RNE pack: v_cvt_pk_bf16_f32 (1 inst for 2 floats; S0 -> low16). Bit-identical to
// bf16_of for finite values (both round-to-nearest-even). [R9: verified absmax unchanged]
__device__ __forceinline__ unsigned cvt_pk2(float lo, float hi) {
    unsigned r;
    asm("v_cvt_pk_bf16_f32 %0, %1, %2" : "=v"(r) : "v"(lo), "v"(hi));
    return r;
}
__device__ __forceinline__ unsigned short bf16s(float v) {
    return (unsigned short)cvt_pk2(v, v);
}

// prep: RNE bf16 single plane of 6 matrices, packed in B-fragment order.
// matrices: 0=W_trk2 1=W_sv2 2=Wc1_bot 3=Wd1 4=Wd2 5=Wc2_bot
__global__ void prep_pack(const float* __restrict__ Wtrk2, const float* __restrict__ Wsv2,
                          const float* __restrict__ Wc1,   const float* __restrict__ Wc2,
                          unsigned short* __restrict__ wsu) {
    const int o = blockIdx.x * 256 + threadIdx.x;
    if (o >= 6 * 16384) return;
    const int m = o >> 14, pos = o & 16383;
    const int j = pos & 7, lane = (pos >> 3) & 63, tile = pos >> 9;
    const int ks = tile >> 3, ni = tile & 7;
    const int d = ks * 32 + (lane >> 4) * 8 + j;
    const int c = ni * 16 + (lane & 15);
    const int e = d * 128 + c;
    float v;
    switch (m) {
        case 0: v = Wtrk2[e]; break;
        case 1: v = Wsv2[e]; break;
        case 2: v = Wc1[16384 + e]; break;
        case 3: v = Wc1[e] - Wc1[16384 + e]; break;
        case 4: v = Wc2[e] - Wc2[16384 + e]; break;
        default: v = Wc2[16384 + e]; break;
    }
    wsu[m * 16384 + pos] = bf16_of(v);
}

#define LOADB1(B_, m_, pos_) B_ = *(const short8*)(wsu + (m_) * 16384 + (pos_))
#define LDFRAG(buf_, r_, k0_) (*(const short8*)&(buf_)[RB((r_), (k0_))])

// Best verified config (R10 bench: 68.6-69.8us/dispatch, e2e 164.2us, WRITE 4.7MB,
// no spill): 50176 B LDS, lb6 -> 3 blocks/CU; P1+P3 and P2+P3b merged; Phase8a kept
// SEPARATE (R11's Phase6+8a merge spilled 43MB: >16 concurrent accs -> scratch).
__global__ __launch_bounds__(TPB, 6)
void fused_mfma(const float* __restrict__ x_sv,  const float* __restrict__ x_trk,
                const float* __restrict__ W_sv1, const float* __restrict__ b_sv1,
                const float* __restrict__ b_sv2,
                const float* __restrict__ W_trk1,const float* __restrict__ b_trk1,
                const float* __restrict__ b_trk2,
                const float* __restrict__ b_c1,  const float* __restrict__ b_c2,
                const float* __restrict__ W_o1,  const float* __restrict__ b_o1,
                const float* __restrict__ W_o2,  const float* __restrict__ b_o2,
                const float* __restrict__ W_o3,  const float* __restrict__ b_o3,
                const float* __restrict__ W_o4,  const float* __restrict__ b_o4,
                const unsigned short* __restrict__ wsu,
                float* __restrict__ out)
{
    __shared__ __align__(16) char sAraw[16896]; // T bf16 -> bsrc2 rows 0..31 (fp32, stride 132)
    __shared__ __align__(16) char sBraw[16384]; // h bf16 -> scores1 -> f1 bf16 -> idx2+pool+head
    __shared__ __align__(16) char sCraw[16896]; // sv_emb bf16 + svnorms + x stage + h_sv bf16 -> bsrc1(132) -> scores2 -> bsrc2 rows 32..63
    short*    sAh = (short*)sAraw;    float* sAf = (float*)sAraw;
    short*    sBh = (short*)sBraw;    float* sBf = (float*)sBraw;
    unsigned* sBu = (unsigned*)sBraw;
    short*    sCh = (short*)sCraw;    float* sCf = (float*)sCraw;

    const int g    = blockIdx.x;
    const int tid  = threadIdx.x;
    const int c128 = tid & 127;
    const int g4   = tid >> 7;
    const int wv   = tid >> 6;          // wave 0..7
    const int lane = tid & 63;
    const int quad = lane >> 4;
    const int ln   = lane & 15;

    // ---- P0: stage inputs (x_trk floats 2048..2559, x_sv floats 2560..2591)
    sCf[2048 + tid] = x_trk[(size_t)g * 512 + tid];
    if (tid < 32) sCf[2560 + tid] = x_sv[(size_t)g * 32 + tid];
    __syncthreads();

    // ---- P1 (+P3 merged): trk MLP layer 1 -> h bf16 in sBh ; sv MLP layer 1 -> sCh[HSV2+]
    {
        float w[8];
        #pragma unroll
        for (int k = 0; k < 8; k++) w[k] = W_trk1[k * 128 + c128];
        const float b1 = b_trk1[c128];
        #pragma unroll
        for (int i = 0; i < 16; i++) {
            const int r = g4 * 16 + i;
            float xr[8];
            *(float4*)&xr[0] = *(const float4*)&sCf[2048 + r * 8];
            *(float4*)&xr[4] = *(const float4*)&sCf[2048 + r * 8 + 4];
            float acc = b1;
            #pragma unroll
            for (int k = 0; k < 8; k++) acc = fmaf(xr[k], w[k], acc);
            sBh[RB(r, c128)] = bf16s(elu_fast(acc));
        }
        // P3: h_sv rows 0..15 -> sCh[HSV2 + RB] (disjoint from x stage & everything live)
        const float w0 = W_sv1[c128], w1 = W_sv1[128 + c128];
        const float bs1 = b_sv1[c128];
        #pragma unroll
        for (int i = 0; i < 4; i++) {
            const int s = g4 * 4 + i;
            sCh[HSV2 + RB(s, c128)] = bf16s(
                elu_fast(fmaf(sCf[2560 + s * 2 + 1], w1, fmaf(sCf[2560 + s * 2], w0, bs1))));
        }
    }
    __syncthreads();

    // ---- P2 (+P3b merged, MFMA): T = relu(h @ W_trk2 + b) -> sAh bf16 ;
    //      sv_emb = relu(h_sv @ W_sv2 + b) -> sCh rows 0..15 ; col-partial norms -> sCf[1024..1151]
    {
        const int mi = wv >> 1, nb = (wv & 1) * 4;
        const int row = mi * 16 + ln;
        f32x4 acc[4];
        #pragma unroll
        for (int t = 0; t < 4; t++) {
            const float bz = b_trk2[(nb + t) * 16 + ln];
            acc[t] = (f32x4){bz, bz, bz, bz};
        }
        #pragma unroll 2
        for (int ks = 0; ks < 4; ks++) {
            const int k0 = ks * 32 + quad * 8;
            const short8 A = LDFRAG(sBh, row, k0);
            #pragma unroll
            for (int t = 0; t < 4; t++) {
                const int pos = ((ks * 8 + (nb + t)) * 64 + lane) * 8;
                short8 B;
                LOADB1(B, 0, pos);
                MFMA1(acc[t], A, B);
            }
        }
        #pragma unroll
        for (int t = 0; t < 4; t++)
            #pragma unroll
            for (int r = 0; r < 4; r++)
                sAh[RB(mi * 16 + quad * 4 + r, (nb + t) * 16 + ln)] =
                    bf16s(fmaxf(acc[t][r], 0.f));
        // P3b: sv_emb (reads h_sv from sCh[HSV2+], writes sCh rows 0..15 + norms sCf[1024+])
        const int ni = wv;
        const float bz2 = b_sv2[ni * 16 + ln];
        f32x4 accs = (f32x4){bz2, bz2, bz2, bz2};
        #pragma unroll 2
        for (int ks = 0; ks < 4; ks++) {
            const int k0 = ks * 32 + quad * 8;
            const short8 A = *(const short8*)&sCh[HSV2 + RB(ln, k0)];
            const int pos = ((ks * 8 + ni) * 64 + lane) * 8;
            short8 B;
            LOADB1(B, 1, pos);
            MFMA1(accs, A, B);
        }
        #pragma unroll
        for (int r = 0; r < 4; r++) {
            const float v = fmaxf(accs[r], 0.f);
            sCh[RB(quad * 4 + r, ni * 16 + ln)] = bf16s(v);
            float p = v * v;
            #pragma unroll
            for (int o = 1; o <= 8; o <<= 1) p += __shfl_xor(p, o, 16);
            if (ln == 0) sCf[1024 + ni * 16 + quad * 4 + r] = p;
        }
    }
    __syncthreads();

    // ---- B1 (MFMA): bsrc1 = sv @ Wc1_bot -> sCf[1984..] stride 132; P4 (waves 0..3): scores1 -> sBf
    {
        const int ni = wv;
        const bool doP4 = (wv < 4);
        f32x4 accB = (f32x4){0.f, 0.f, 0.f, 0.f};
        f32x4 accS = (f32x4){0.f, 0.f, 0.f, 0.f};
        #pragma unroll 2
        for (int ks = 0; ks < 4; ks++) {
            const int k0 = ks * 32 + quad * 8;
            const short8 S = LDFRAG(sCh, ln, k0);
            const int pos = ((ks * 8 + ni) * 64 + lane) * 8;
            short8 B;
            LOADB1(B, 2, pos);
            MFMA1(accB, S, B);
            if (doP4) {
                const short8 T = LDFRAG(sAh, wv * 16 + ln, k0);
                MFMA1(accS, T, S);
            }
        }
        #pragma unroll
        for (int r = 0; r < 4; r++)
            sCf[1984 + (quad * 4 + r) * BSTRIDE + ni * 16 + ln] = accB[r];
        if (doP4) {
            float nsv = 0.f;
            #pragma unroll
            for (int p = 0; p < 8; p++) nsv += sCf[1024 + p * 16 + ln];
            #pragma unroll
            for (int r = 0; r < 4; r++)
                sBf[(wv * 16 + quad * 4 + r) * 17 + ln] = fmaf(-2.f, accS[r], nsv);
        }
    }
    __syncthreads();

    // ---- topk1: top-8 of 16 (shfl) -> packs sBu[1088+q]
    {
        const int q  = tid >> 3;
        const int s0 = tid & 7;
        float sc0 = sBf[q * 17 + s0];
        float sc1 = sBf[q * 17 + s0 + 8];
        unsigned pack1 = 0u;
        #pragma unroll
        for (int r = 0; r < 8; r++) {
            float bv = sc0; int bs = s0;
            if (sc1 < bv) { bv = sc1; bs = s0 + 8; }
            #pragma unroll
            for (int o = 1; o <= 4; o <<= 1) {
                const float ov = __shfl_xor(bv, o, 8);
                const int   os = __shfl_xor(bs, o, 8);
                if (ov < bv || (ov == bv && os < bs)) { bv = ov; bs = os; }
            }
            pack1 |= (unsigned)bs << (4 * r);
            if (bs == s0)     sc0 = INF_F;
            if (bs == s0 + 8) sc1 = INF_F;
        }
        if (s0 == 0) sBu[1088 + q] = pack1;
    }
    __syncthreads();

    // ---- Phase6 (MFMA): a1 = T @ Wd1 + b1 ; f1 = elu(a1 + max bsrc1[idx]) -> sBh bf16;
    //      f1-norm halves -> sCf[0..127]
    {
        const int mi = wv >> 1, nb = (wv & 1) * 4;
        const int row = mi * 16 + ln;
        f32x4 a1acc[4];
        #pragma unroll
        for (int t = 0; t < 4; t++) {
            const float bz1 = b_c1[(nb + t) * 16 + ln];
            a1acc[t] = (f32x4){bz1, bz1, bz1, bz1};
        }
        #pragma unroll 2
        for (int ks = 0; ks < 4; ks++) {
            const int k0 = ks * 32 + quad * 8;
            const short8 A = LDFRAG(sAh, row, k0);
            #pragma unroll
            for (int t = 0; t < 4; t++) {
                const int pos = ((ks * 8 + (nb + t)) * 64 + lane) * 8;
                short8 B;
                LOADB1(B, 3, pos);
                MFMA1(a1acc[t], A, B);
            }
        }
        // read packs into regs BEFORE barrier (f1 writes overwrite sBu[1088..])
        unsigned pk[4];
        #pragma unroll
        for (int r = 0; r < 4; r++) pk[r] = sBu[1088 + mi * 16 + quad * 4 + r];
        __syncthreads();
        float np[4] = {0.f, 0.f, 0.f, 0.f};
        const int ccb = nb * 16 + ln;   // col for t: ccb + 16*t
        const float* b1base = &sCf[1984 + ccb];
        #pragma unroll
        for (int r = 0; r < 4; r++) {
            float mx0 = -INF_F, mx1 = -INF_F, mx2 = -INF_F, mx3 = -INF_F;
            #pragma unroll
            for (int j = 0; j < 8; j++) {
                const int s = (int)((pk[r] >> (4 * j)) & 15u);
                const float* rp = b1base + s * BSTRIDE;
                mx0 = fmaxf(mx0, rp[0]);
                mx1 = fmaxf(mx1, rp[16]);
                mx2 = fmaxf(mx2, rp[32]);
                mx3 = fmaxf(mx3, rp[48]);
            }
            const float mxa[4] = {mx0, mx1, mx2, mx3};
            #pragma unroll
            for (int t = 0; t < 4; t++) {
                const float f = elu_fast(a1acc[t][r] + mxa[t]);
                sBh[RB(mi * 16 + quad * 4 + r, ccb + 16 * t)] = bf16s(f);
                np[r] = fmaf(f, f, np[r]);
            }
        }
        #pragma unroll
        for (int r = 0; r < 4; r++) {
            #pragma unroll
            for (int o = 1; o <= 8; o <<= 1) np[r] += __shfl_xor(np[r], o, 16);
            if (ln == 0) sCf[(wv & 1) * 64 + mi * 16 + quad * 4 + r] = np[r];
        }
    }
    __syncthreads();

    // ---- Phase7 (MFMA): scores2[q][s] = n_s - 2 T_q . f1_s -> sCf[q*64+s]
    {
        const int mi = wv >> 1, nia = (wv & 1) * 2;
        const int row = mi * 16 + ln;
        float ns[2];
        #pragma unroll
        for (int u = 0; u < 2; u++) {
            const int s = (nia + u) * 16 + ln;
            ns[u] = sCf[s] + sCf[64 + s];
        }
        __syncthreads();   // norms read before scores overwrite sCf
        f32x4 acc[2];
        acc[0] = (f32x4){0.f, 0.f, 0.f, 0.f};
        acc[1] = (f32x4){0.f, 0.f, 0.f, 0.f};
        #pragma unroll 2
        for (int ks = 0; ks < 4; ks++) {
            const int k0 = ks * 32 + quad * 8;
            const short8 A = LDFRAG(sAh, row, k0);
            #pragma unroll
            for (int u = 0; u < 2; u++) {
                const short8 Bf = LDFRAG(sBh, (nia + u) * 16 + ln, k0);
                MFMA1(acc[u], A, Bf);
            }
        }
        #pragma unroll
        for (int u = 0; u < 2; u++) {
            const int s = (nia + u) * 16 + ln;
            #pragma unroll
            for (int r = 0; r < 4; r++)
                sCf[(mi * 16 + quad * 4 + r) * 64 + s] = fmaf(-2.f, acc[u][r], ns[u]);
        }
    }
    __syncthreads();

    // ---- topk2: top-8 of 64 (shfl) ; lo2/hi2 kept in regs until post-P8d handoff
    unsigned lo2, hi2;
    {
        const int q = tid >> 3;
        const int j = tid & 7;
        float v[8];
        *(float4*)&v[0] = *(const float4*)&sCf[q * 64 + 8 * j];
        *(float4*)&v[4] = *(const float4*)&sCf[q * 64 + 8 * j + 4];
        lo2 = 0u; hi2 = 0u;
        #pragma unroll
        for (int r = 0; r < 8; r++) {
            float bv = v[0]; int bs = 8 * j;
            #pragma unroll
            for (int t = 1; t < 8; t++)
                if (v[t] < bv) { bv = v[t]; bs = 8 * j + t; }
            #pragma unroll
            for (int o = 1; o <= 4; o <<= 1) {
                const float ov = __shfl_xor(bv, o, 8);
                const int   os = __shfl_xor(bs, o, 8);
                if (ov < bv || (ov == bv && os < bs)) { bv = ov; bs = os; }
            }
            if (r < 4) lo2 |= (unsigned)bs << (8 * r);
            else       hi2 |= (unsigned)bs << (8 * (r - 4));
            #pragma unroll
            for (int t = 0; t < 8; t++)
                if (bs == 8 * j + t) v[t] = INF_F;
        }
    }
    __syncthreads();   // all score reads done; sC scores region dead

    // ---- Phase8a (MFMA): a2 = T @ Wd2 + b2 ; keep as 8 packed-bf16 u32 in REGISTERS
    unsigned a2p[8];
    {
        const int mi = wv >> 1, nb = (wv & 1) * 4;
        const int row = mi * 16 + ln;
        f32x4 a2acc[4];
        #pragma unroll
        for (int t = 0; t < 4; t++) {
            const float bz2 = b_c2[(nb + t) * 16 + ln];
            a2acc[t] = (f32x4){bz2, bz2, bz2, bz2};
        }
        #pragma unroll 2
        for (int ks = 0; ks < 4; ks++) {
            const int k0 = ks * 32 + quad * 8;
            const short8 A = LDFRAG(sAh, row, k0);
            #pragma unroll
            for (int t = 0; t < 4; t++) {
                const int pos = ((ks * 8 + (nb + t)) * 64 + lane) * 8;
                short8 B;
                LOADB1(B, 4, pos);
                MFMA1(a2acc[t], A, B);
            }
        }
        #pragma unroll
        for (int t = 0; t < 4; t++) {
            a2p[2 * t]     = cvt_pk2(a2acc[t][0], a2acc[t][1]);
            a2p[2 * t + 1] = cvt_pk2(a2acc[t][2], a2acc[t][3]);
        }
    }
    __syncthreads();   // a2 done reading T before P8d overwrites sA

    // ---- P8d (MFMA): bsrc2 = f1 @ Wc2_bot, fp32 stride 132, rows 0..31 -> sAf, 32..63 -> sCf
    {
        const int mi = wv >> 1, nb = (wv & 1) * 4;
        const int row = mi * 16 + ln;
        f32x4 acc[4];
        #pragma unroll
        for (int t = 0; t < 4; t++) acc[t] = (f32x4){0.f, 0.f, 0.f, 0.f};
        #pragma unroll 2
        for (int ks = 0; ks < 4; ks++) {
            const int k0 = ks * 32 + quad * 8;
            const short8 A = LDFRAG(sBh, row, k0);
            #pragma unroll
            for (int t = 0; t < 4; t++) {
                const int pos = ((ks * 8 + (nb + t)) * 64 + lane) * 8;
                short8 B;
                LOADB1(B, 5, pos);
                MFMA1(acc[t], A, B);
            }
        }
        float* bp = (mi < 2) ? sAf : sCf;   // wave-uniform
        const int ccb = nb * 16 + ln;
        #pragma unroll
        for (int t = 0; t < 4; t++)
            #pragma unroll
            for (int r = 0; r < 4; r++) {
                const int rr = mi * 16 + quad * 4 + r;
                bp[(rr & 31) * BSTRIDE + ccb + 16 * t] = acc[t][r];
            }
    }
    __syncthreads();   // f1 now dead -> sB free for idx2 handoff

    // ---- idx2 handoff -> sBu[1024 + 2q] (dead f1 space)
    if ((tid & 7) == 0) {
        const int q = tid >> 3;
        sBu[1024 + 2 * q]     = lo2;
        sBu[1024 + 2 * q + 1] = hi2;
    }
    __syncthreads();

    // ---- Phase9: f2 = elu(a2 + max bsrc2[idx]) ; pool -> sBf[0..511]
    {
        const int mi = wv >> 1, nb = (wv & 1) * 4;
        float ps[4] = {0.f, 0.f, 0.f, 0.f};
        const int ccb = nb * 16 + ln;
        const float* bA = &sAf[ccb];
        const float* bC = &sCf[ccb];
        #pragma unroll
        for (int r = 0; r < 4; r++) {
            const int rr = mi * 16 + quad * 4 + r;
            const unsigned plo = sBu[1024 + 2 * rr];
            const unsigned phi = sBu[1024 + 2 * rr + 1];
            float mx0 = -INF_F, mx1 = -INF_F, mx2 = -INF_F, mx3 = -INF_F;
            #pragma unroll
            for (int j = 0; j < 8; j++) {
                const int s = (int)(((j < 4) ? (plo >> (8 * j))
                                             : (phi >> (8 * (j - 4)))) & 63u);
                const float* rp = ((s < 32) ? bA : bC) + (s & 31) * BSTRIDE;
                mx0 = fmaxf(mx0, rp[0]);
                mx1 = fmaxf(mx1, rp[16]);
                mx2 = fmaxf(mx2, rp[32]);
                mx3 = fmaxf(mx3, rp[48]);
            }
            const float mxa[4] = {mx0, mx1, mx2, mx3};
            #pragma unroll
            for (int t = 0; t < 4; t++) {
                const unsigned u = a2p[2 * t + (r >> 1)];
                const float a2v = __uint_as_float((r & 1) ? (u & 0xFFFF0000u) : (u << 16));
                ps[t] += elu_fast(a2v + mxa[t]);
            }
        }
        #pragma unroll
        for (int t = 0; t < 4; t++) {
            ps[t] += __shfl_xor(ps[t], 16, 64);
            ps[t] += __shfl_xor(ps[t], 32, 64);
        }
        if (lane < 16)
            #pragma unroll
            for (int t = 0; t < 4; t++)
                sBf[mi * 128 + (nb + t) * 16 + lane] = ps[t];
    }
    __syncthreads();

    // ---- Head
    if (tid < 128) {
        const float p = (sBf[tid] + sBf[128 + tid] + sBf[256 + tid] + sBf[384 + tid]) * (1.f / 64.f);
        sBf[512 + tid] = p;
    }
    __syncthreads();
    if (tid < 64) {
        float acc = b_o1[tid];
        for (int d = 0; d < 128; d++) acc = fmaf(sBf[512 + d], W_o1[d * 64 + tid], acc);
        sBf[640 + tid] = elu_fast(acc);
    }
    __syncthreads();
    if (tid < 32) {
        float acc = b_o2[tid];
        for (int d = 0; d < 64; d++) acc = fmaf(sBf[640 + d], W_o2[d * 32 + tid], acc);
        sBf[704 + tid] = elu_fast(acc);
    }
    __syncthreads();
    if (tid < 4) {
        float acc = b_o3[tid];
        for (int d = 0; d < 32; d++) acc = fmaf(sBf[704 + d], W_o3[d * 4 + tid], acc);
        sBf[736 + tid] = elu_fast(acc);
    }
    __syncthreads();
    if (tid == 0) {
        float acc = b_o4[0];
        #pragma unroll
        for (int d = 0; d < 4; d++) acc = fmaf(sBf[736 + d], W_o4[d], acc);
        out[g] = acc;
        out[G_ + g] = (float)g;
    }
}

// ================= vector fallback (round-4 kernel, inline weight diffs) =================
#define ROTV(r, d)    ((r)*128 + (((d) + 4*(r)) & 127))
#define BS1V(s, c)    (2048 + (s)*128 + (((c) + 4*(s)) & 127))
__global__ __launch_bounds__(TPB, 2)
void fused_vec(const float* __restrict__ x_sv,  const float* __restrict__ x_trk,
               const float* __restrict__ W_sv1, const float* __restrict__ b_sv1,
               const float* __restrict__ W_sv2, const float* __restrict__ b_sv2,
               const float* __restrict__ W_trk1,const float* __restrict__ b_trk1,
               const float* __restrict__ W_trk2,const float* __restrict__ b_trk2,
               const float* __restrict__ W_c1,  const float* __restrict__ b_c1,
               const float* __restrict__ W_c2,  const float* __restrict__ b_c2,
               const float* __restrict__ W_o1,  const float* __restrict__ b_o1,
               const float* __restrict__ W_o2,  const float* __restrict__ b_o2,
               const float* __restrict__ W_o3,  const float* __restrict__ b_o3,
               const float* __restrict__ W_o4,  const float* __restrict__ b_o4,
               float* __restrict__ out)
{
    __shared__ float sA[8192];
    __shared__ float sB[8192];
    __shared__ float sC[4096];
    const int g    = blockIdx.x;
    const int tid  = threadIdx.x;
    const int c128 = tid & 127;
    const int g4   = tid >> 7;
    const int cq   = tid & 31;
    const int c0   = cq * 4;
    const int rg   = tid >> 5;
    const int lane_hi = tid & 32;

    sC[2048 + tid] = x_trk[(size_t)g * 512 + tid];
    if (tid < 32) sC[2560 + tid] = x_sv[(size_t)g * 32 + tid];
    __syncthreads();
    {
        float w[8];
        #pragma unroll
        for (int k = 0; k < 8; k++) w[k] = W_trk1[k * 128 + c128];
        const float b1 = b_trk1[c128];
        #pragma unroll
        for (int i = 0; i < 16; i++) {
            const int r = g4 * 16 + i;
            float acc = b1;
            #pragma unroll
            for (int k = 0; k < 8; k++) acc = fmaf(sC[2048 + r * 8 + k], w[k], acc);
            sB[r * 128 + c128] = elu_ref(acc);
        }
    }
    __syncthreads();
    {
        const int r0 = rg * 4;
        float4 acc[4];
        const float4 bz = *(const float4*)&b_trk2[c0];
        #pragma unroll
        for (int i = 0; i < 4; i++) acc[i] = bz;
        for (int d0 = 0; d0 < 128; d0 += 4) {
            const float4 w0 = *(const float4*)&W_trk2[(d0 + 0) * 128 + c0];
            const float4 w1 = *(const float4*)&W_trk2[(d0 + 1) * 128 + c0];
            const float4 w2 = *(const float4*)&W_trk2[(d0 + 2) * 128 + c0];
            const float4 w3 = *(const float4*)&W_trk2[(d0 + 3) * 128 + c0];
            #pragma unroll
            for (int i = 0; i < 4; i++) {
                const float4 h = *(const float4*)&sB[(r0 + i) * 128 + d0];
                FMA4(acc[i], h.x, w0); FMA4(acc[i], h.y, w1);
                FMA4(acc[i], h.z, w2); FMA4(acc[i], h.w, w3);
            }
        }
        #pragma unroll
        for (int i = 0; i < 4; i++) {
            float4 r;
            r.x = fmaxf(acc[i].x, 0.f); r.y = fmaxf(acc[i].y, 0.f);
            r.z = fmaxf(acc[i].z, 0.f); r.w = fmaxf(acc[i].w, 0.f);
            *(float4*)&sA[ROTV(r0 + i, c0)] = r;
        }
    }
    __syncthreads();
    {
        const float w0 = W_sv1[c128], w1 = W_sv1[128 + c128];
        const float b1 = b_sv1[c128];
        #pragma unroll
        for (int i = 0; i < 4; i++) {
            const int s = g4 * 4 + i;
            sB[s * 128 + c128] =
                elu_ref(fmaf(sC[2560 + s * 2 + 1], w1, fmaf(sC[2560 + s * 2], w0, b1)));
        }
    }
    __syncthreads();
    {
        const int s = rg;
        float4 acc = *(const float4*)&b_sv2[c0];
        for (int d0 = 0; d0 < 128; d0 += 4) {
            const float4 w0 = *(const float4*)&W_sv2[(d0 + 0) * 128 + c0];
            const float4 w1 = *(const float4*)&W_sv2[(d0 + 1) * 128 + c0];
            const float4 w2 = *(const float4*)&W_sv2[(d0 + 2) * 128 + c0];
            const float4 w3 = *(const float4*)&W_sv2[(d0 + 3) * 128 + c0];
            const float4 h = *(const float4*)&sB[s * 128 + d0];
            FMA4(acc, h.x, w0); FMA4(acc, h.y, w1);
            FMA4(acc, h.z, w2); FMA4(acc, h.w, w3);
        }
        float4 r;
        r.x = fmaxf(acc.x, 0.f); r.y = fmaxf(acc.y, 0.f);
        r.z = fmaxf(acc.z, 0.f); r.w = fmaxf(acc.w, 0.f);
        *(float4*)&sC[ROTV(s, c0)] = r;
    }
    __syncthreads();
    unsigned pack1;
    {
        {
            const int s = rg;
            float4 acc = {0.f, 0.f, 0.f, 0.f};
            for (int d0 = 0; d0 < 128; d0 += 4) {
                const float4 e  = *(const float4*)&sC[ROTV(s, d0)];
                const float4 w0 = *(const float4*)&W_c1[(128 + d0 + 0) * 128 + c0];
                const float4 w1 = *(const float4*)&W_c1[(128 + d0 + 1) * 128 + c0];
                const float4 w2 = *(const float4*)&W_c1[(128 + d0 + 2) * 128 + c0];
                const float4 w3 = *(const float4*)&W_c1[(128 + d0 + 3) * 128 + c0];
                FMA4(acc, e.x, w0); FMA4(acc, e.y, w1);
                FMA4(acc, e.z, w2); FMA4(acc, e.w, w3);
            }
            *(float4*)&sC[BS1V(s, c0)] = acc;
        }
        const int q  = tid >> 3;
        const int s0 = tid & 7;
        float d0a = 0.f, d1a = 0.f, n0 = 0.f, n1 = 0.f;
        for (int d0 = 0; d0 < 128; d0 += 4) {
            const float4 t  = *(const float4*)&sA[ROTV(q, d0)];
            const float4 v0 = *(const float4*)&sC[ROTV(s0, d0)];
            const float4 v1 = *(const float4*)&sC[ROTV(s0 + 8, d0)];
            d0a += t.x * v0.x + t.y * v0.y + t.z * v0.z + t.w * v0.w;
            d1a += t.x * v1.x + t.y * v1.y + t.z * v1.z + t.w * v1.w;
            n0  += v0.x * v0.x + v0.y * v0.y + v0.z * v0.z + v0.w * v0.w;
            n1  += v1.x * v1.x + v1.y * v1.y + v1.z * v1.z + v1.w * v1.w;
        }
        float sc0 = fmaf(-2.f, d0a, n0);
        float sc1 = fmaf(-2.f, d1a, n1);
        pack1 = 0u;
        #pragma unroll
        for (int r = 0; r < 8; r++) {
            float bv = sc0; int bs = s0;
            if (sc1 < bv) { bv = sc1; bs = s0 + 8; }
            #pragma unroll
            for (int o = 1; o <= 4; o <<= 1) {
                const float ov = __shfl_xor(bv, o, 8);
                const int   os = __shfl_xor(bs, o, 8);
                if (ov < bv || (ov == bv && os < bs)) { bv = ov; bs = os; }
            }
            pack1 |= (unsigned)bs << (4 * r);
            if (bs == s0)     sc0 = INF_F;
            if (bs == s0 + 8) sc1 = INF_F;
        }
    }
    __syncthreads();
    float4 a2v[4];
    {
        const int q0 = rg * 4;
        float4 a1[4];
        const float4 bc1 = *(const float4*)&b_c1[c0];
        const float4 bc2 = *(const float4*)&b_c2[c0];
        #pragma unroll
        for (int i = 0; i < 4; i++) { a1[i] = bc1; a2v[i] = bc2; }
        for (int d0 = 0; d0 < 128; d0 += 4) {
            float4 t[4];
            #pragma unroll
            for (int i = 0; i < 4; i++) t[i] = *(const float4*)&sA[ROTV(q0 + i, d0)];
            #pragma unroll
            for (int dj = 0; dj < 4; dj++) {
                float4 wv;
                const float4 wa = *(const float4*)&W_c1[(d0 + dj) * 128 + c0];
                const float4 wb = *(const float4*)&W_c1[(128 + d0 + dj) * 128 + c0];
                wv.x = wa.x - wb.x; wv.y = wa.y - wb.y;
                wv.z = wa.z - wb.z; wv.w = wa.w - wb.w;
                FMA4(a1[0], ((const float*)&t[0])[dj], wv);
                FMA4(a1[1], ((const float*)&t[1])[dj], wv);
                FMA4(a1[2], ((const float*)&t[2])[dj], wv);
                FMA4(a1[3], ((const float*)&t[3])[dj], wv);
            }
            #pragma unroll
            for (int dj = 0; dj < 4; dj++) {
                float4 wv;
                const float4 wa = *(const float4*)&W_c2[(d0 + dj) * 128 + c0];
                const float4 wb = *(const float4*)&W_c2[(128 + d0 + dj) * 128 + c0];
                wv.x = wa.x - wb.x; wv.y = wa.y - wb.y;
                wv.z = wa.z - wb.z; wv.w = wa.w - wb.w;
                FMA4(a2v[0], ((const float*)&t[0])[dj], wv);
                FMA4(a2v[1], ((const float*)&t[1])[dj], wv);
                FMA4(a2v[2], ((const float*)&t[2])[dj], wv);
                FMA4(a2v[3], ((const float*)&t[3])[dj], wv);
            }
        }
        #pragma unroll
        for (int i = 0; i < 4; i++) {
            const int q = q0 + i;
            const unsigned pk = __shfl(pack1, 8 * i + lane_hi);
            float4 m = {-INF_F, -INF_F, -INF_F, -INF_F};
            #pragma unroll
            for (int j = 0; j < 8; j++) {
                const int s = (int)((pk >> (4 * j)) & 15u);
                const float4 b = *(const float4*)&sC[BS1V(s, c0)];
                MAX4(m, b);
            }
            float4 f;
            f.x = elu_ref(a1[i].x + m.x); f.y = elu_ref(a1[i].y + m.y);
            f.z = elu_ref(a1[i].z + m.z); f.w = elu_ref(a1[i].w + m.w);
            *(float4*)&sB[ROTV(q, c0)] = f;
        }
    }
    __syncthreads();
    {
        const int s  = tid & 63;
        const int q0 = (tid >> 6) * 8;
        float acc[8];
        #pragma unroll
        for (int i = 0; i < 8; i++) acc[i] = 0.f;
        float nrm = 0.f;
        for (int d0 = 0; d0 < 128; d0 += 4) {
            const float4 f = *(const float4*)&sB[ROTV(s, d0)];
            nrm = fmaf(f.x, f.x, nrm); nrm = fmaf(f.y, f.y, nrm);
            nrm = fmaf(f.z, f.z, nrm); nrm = fmaf(f.w, f.w, nrm);
            #pragma unroll
            for (int i = 0; i < 8; i++) {
                const float4 t = *(const float4*)&sA[ROTV(q0 + i, d0)];
                acc[i] = fmaf(t.x, f.x, acc[i]); acc[i] = fmaf(t.y, f.y, acc[i]);
                acc[i] = fmaf(t.z, f.z, acc[i]); acc[i] = fmaf(t.w, f.w, acc[i]);
            }
        }
        #pragma unroll
        for (int i = 0; i < 8; i++)
            sC[(q0 + i) * 64 + s] = fmaf(-2.f, acc[i], nrm);
    }
    __syncthreads();
    unsigned lo2, hi2;
    {
        const int q = tid >> 3;
        const int j = tid & 7;
        float v[8];
        *(float4*)&v[0] = *(const float4*)&sC[q * 64 + 8 * j];
        *(float4*)&v[4] = *(const float4*)&sC[q * 64 + 8 * j + 4];
        lo2 = 0u; hi2 = 0u;
        #pragma unroll
        for (int r = 0; r < 8; r++) {
            float bv = v[0]; int bs = 8 * j;
            #pragma unroll
            for (int t = 1; t < 8; t++)
                if (v[t] < bv) { bv = v[t]; bs = 8 * j + t; }
            #pragma unroll
            for (int o = 1; o <= 4; o <<= 1) {
                const float ov = __shfl_xor(bv, o, 8);
                const int   os = __shfl_xor(bs, o, 8);
                if (ov < bv || (ov == bv && os < bs)) { bv = ov; bs = os; }
            }
            if (r < 4) lo2 |= (unsigned)bs << (8 * r);
            else       hi2 |= (unsigned)bs << (8 * (r - 4));
            #pragma unroll
            for (int t = 0; t < 8; t++)
                if (bs == 8 * j + t) v[t] = INF_F;
        }
        const int r0 = rg * 4;
        float4 acc[4];
        #pragma unroll
        for (int i = 0; i < 4; i++) acc[i] = make_float4(0.f, 0.f, 0.f, 0.f);
        for (int d0 = 0; d0 < 128; d0 += 4) {
            const float4 w0 = *(const float4*)&W_c2[(128 + d0 + 0) * 128 + c0];
            const float4 w1 = *(const float4*)&W_c2[(128 + d0 + 1) * 128 + c0];
            const float4 w2 = *(const float4*)&W_c2[(128 + d0 + 2) * 128 + c0];
            const float4 w3 = *(const float4*)&W_c2[(128 + d0 + 3) * 128 + c0];
            #pragma unroll
            for (int i = 0; i < 4; i++) {
                const float4 f = *(const float4*)&sB[ROTV(r0 + i, d0)];
                FMA4(acc[i], f.x, w0); FMA4(acc[i], f.y, w1);
                FMA4(acc[i], f.z, w2); FMA4(acc[i], f.w, w3);
            }
        }
        #pragma unroll
        for (int i = 0; i < 4; i++)
            *(float4*)&sA[ROTV(r0 + i, c0)] = acc[i];
    }
    __syncthreads();
    {
        const int q0 = rg * 4;
        float4 ps = {0.f, 0.f, 0.f, 0.f};
        #pragma unroll
        for (int i = 0; i < 4; i++) {
            const unsigned plo = __shfl(lo2, 8 * i + lane_hi);
            const unsigned phi = __shfl(hi2, 8 * i + lane_hi);
            float4 m = {-INF_F, -INF_F, -INF_F, -INF_F};
            #pragma unroll
            for (int j = 0; j < 8; j++) {
                const int s = (int)(((j < 4) ? (plo >> (8 * j)) : (phi >> (8 * (j - 4)))) & 63u);
                const float4 b = *(const float4*)&sA[ROTV(s, c0)];
                MAX4(m, b);
            }
            ps.x += elu_ref(a2v[i].x + m.x); ps.y += elu_ref(a2v[i].y + m.y);
            ps.z += elu_ref(a2v[i].z + m.z); ps.w += elu_ref(a2v[i].w + m.w);
        }
        *(float4*)&sB[rg * 128 + c0] = ps;
    }
    __syncthreads();
    if (tid < 128) {
        float p = 0.f;
        #pragma unroll
        for (int t = 0; t < 16; t++) p += sB[t * 128 + tid];
        sB[2048 + tid] = p * (1.f / 64.f);
    }
    __syncthreads();
    if (tid < 64) {
        float acc = b_o1[tid];
        for (int d = 0; d < 128; d++) acc = fmaf(sB[2048 + d], W_o1[d * 64 + tid], acc);
        sB[2176 + tid] = elu_ref(acc);
    }
    __syncthreads();
    if (tid < 32) {
        float acc = b_o2[tid];
        for (int d = 0; d < 64; d++) acc = fmaf(sB[2176 + d], W_o2[d * 32 + tid], acc);
        sB[2240 + tid] = elu_ref(acc);
    }
    __syncthreads();
    if (tid < 4) {
        float acc = b_o3[tid];
        for (int d = 0; d < 32; d++) acc = fmaf(sB[2240 + d], W_o3[d * 4 + tid], acc);
        sB[2272 + tid] = elu_ref(acc);
    }
    __syncthreads();
    if (tid == 0) {
        float acc = b_o4[0];
        #pragma unroll
        for (int d = 0; d < 4; d++) acc = fmaf(sB[2272 + d], W_o4[d], acc);
        out[g] = acc;
        out[G_ + g] = (float)g;
    }
}

extern "C" void kernel_launch(void* const* d_in, const int* in_sizes, int n_in,
                              void* d_out, int out_size, void* d_ws, size_t ws_size,
                              hipStream_t stream) {
    const float* x_sv   = (const float*)d_in[0];
    const float* x_trk  = (const float*)d_in[1];
    const float* W_sv1  = (const float*)d_in[2];
    const float* b_sv1  = (const float*)d_in[3];
    const float* W_sv2  = (const float*)d_in[4];
    const float* b_sv2  = (const float*)d_in[5];
    const float* W_trk1 = (const float*)d_in[6];
    const float* b_trk1 = (const float*)d_in[7];
    const float* W_trk2 = (const float*)d_in[8];
    const float* b_trk2 = (const float*)d_in[9];
    const float* W_c1   = (const float*)d_in[10];
    const float* b_c1   = (const float*)d_in[11];
    const float* W_c2   = (const float*)d_in[12];
    const float* b_c2   = (const float*)d_in[13];
    const float* W_o1   = (const float*)d_in[14];
    const float* b_o1   = (const float*)d_in[15];
    const float* W_o2   = (const float*)d_in[16];
    const float* b_o2   = (const float*)d_in[17];
    const float* W_o3   = (const float*)d_in[18];
    const float* b_o3   = (const float*)d_in[19];
    const float* W_o4   = (const float*)d_in[20];
    const float* b_o4   = (const float*)d_in[21];
    float* out = (float*)d_out;

    const size_t WS_NEED = (size_t)6 * 16384 * sizeof(unsigned short); // 192 KB
    if (ws_size >= WS_NEED && d_ws != nullptr) {
        unsigned short* wsu = (unsigned short*)d_ws;
        prep_pack<<<384, 256, 0, stream>>>(W_trk2, W_sv2, W_c1, W_c2, wsu);
        fused_mfma<<<G_, TPB, 0, stream>>>(x_sv, x_trk, W_sv1, b_sv1, b_sv2,
                                           W_trk1, b_trk1, b_trk2, b_c1, b_c2,
                                           W_o1, b_o1, W_o2, b_o2, W_o3, b_o3,
                                           W_o4, b_o4, wsu, out);
    } else {
        fused_vec<<<G_, TPB, 0, stream>>>(x_sv, x_trk, W_sv1, b_sv1, W_sv2, b_sv2,
                                          W_trk1, b_trk1, W_trk2, b_trk2,
                                          W_c1, b_c1, W_c2, b_c2,
                                          W_o1, b_o1, W_o2, b_o2, W_o3, b_o3,
                                          W_o4, b_o4, out);
    }
}